// Round 7
// baseline (6362.503 us; speedup 1.0000x reference)
//
#include <hip/hip_runtime.h>
#include <math.h>

#define N_  2048
#define T_  200
#define D_  16
#define H_  64
#define C2_ 128   // 2*H
#define BM  8
#define NTHR 1024
#define NBLK 256

// X slot: [128][2048] bf16 + 4KB guard gap
#define SLOT_USH ((size_t)C2_ * N_ + 2048)

typedef unsigned short ushort_t;
typedef short bf16x8 __attribute__((ext_vector_type(8)));
typedef float f32x4 __attribute__((ext_vector_type(4)));

// ---- weight blob layout (ushort offsets) ----
#define W_HC 0        // W_h_cur^T  [64][64]  swz8
#define W_HP 4096     // W_h_prev^T [64][64]  swz8
#define W_CC 8192     // W_c_cur^T  [64][64]  swz8
#define W_CP 12288    // W_c_prev^T [64][64]  swz8
#define W_G  16384    // [Wgh^T ; Wgc^T] [128][64] swz8
#define W_R  24576    // R^T [256][64] swz8
#define W_K  40960    // K^T [256][16] swz2  (read from GLOBAL in epiC)
#define W_USH 45056   // then 512 fp32 biases
#define BLOB_BYTES 92160

// LDS weight image: [0,40960) weights (no W_K) + 512 f32 biases = 41984 ush
#define WL_USH 41984

__device__ __forceinline__ float sig_(float x) {
    return __fdividef(1.0f, 1.0f + __expf(-x));
}
__device__ __forceinline__ float tanh_(float x) {
    float e = __expf(-2.0f * fabsf(x));
    float t = __fdividef(1.0f - e, 1.0f + e);
    return copysignf(t, x);
}
__device__ __forceinline__ ushort_t f2bf(float f) {
    unsigned u = __float_as_uint(f);
    u = (u + 0x7FFFu + ((u >> 16) & 1u)) >> 16;
    return (ushort_t)u;
}
__device__ __forceinline__ float blo(unsigned u){ return __uint_as_float(u << 16); }
__device__ __forceinline__ float bhi(unsigned u){ return __uint_as_float(u & 0xFFFF0000u); }

__device__ __forceinline__ void gload16(const void* g, void* l) {
    __builtin_amdgcn_global_load_lds(
        (const __attribute__((address_space(1))) unsigned int*)g,
        (__attribute__((address_space(3))) unsigned int*)l, 16, 0, 0);
}

// ---- A (fp32) -> A (bf16); zero barrier counter ----
__global__ __launch_bounds__(256) void convert_A_kernel(
    const float* __restrict__ A, ushort_t* __restrict__ Abf,
    unsigned* __restrict__ cnt)
{
    if (blockIdx.x == 0 && threadIdx.x == 0)
        __hip_atomic_store(cnt, 0u, __ATOMIC_RELAXED, __HIP_MEMORY_SCOPE_AGENT);
    size_t i = ((size_t)blockIdx.x * 256 + threadIdx.x) * 4;
    float4 v = *(const float4*)(A + i);
    ushort4 o;
    o.x = f2bf(v.x); o.y = f2bf(v.y); o.z = f2bf(v.z); o.w = f2bf(v.w);
    *(ushort4*)(Abf + i) = o;
}

// ---- pack weights (unchanged layout) ----
__global__ __launch_bounds__(256) void convert_W_kernel(
    const float* __restrict__ Whc, const float* __restrict__ Whp,
    const float* __restrict__ Wcc, const float* __restrict__ Wcp,
    const float* __restrict__ Wgh, const float* __restrict__ Wgc,
    const float* __restrict__ R,   const float* __restrict__ Kw,
    const float* __restrict__ bh,  const float* __restrict__ bc,
    const float* __restrict__ bgh, const float* __restrict__ bgc,
    const float* __restrict__ bl,
    ushort_t* __restrict__ blob)
{
    const int stride = gridDim.x * 256;
    const int gid = blockIdx.x * 256 + threadIdx.x;
    for (int idx = gid; idx < 4096; idx += stride) {
        int k = idx >> 6, c = idx & 63;
        int dst = c * 64 + ((((k >> 3) ^ c) & 7) << 3) + (k & 7);
        blob[W_HC + dst] = f2bf(Whc[idx]);
        blob[W_HP + dst] = f2bf(Whp[idx]);
        blob[W_CC + dst] = f2bf(Wcc[idx]);
        blob[W_CP + dst] = f2bf(Wcp[idx]);
        blob[W_G + dst]        = f2bf(Wgh[idx]);
        blob[W_G + 4096 + dst] = f2bf(Wgc[idx]);
    }
    for (int idx = gid; idx < 16384; idx += stride) {
        int k = idx >> 8, gc = idx & 255;
        int dst = gc * 64 + ((((k >> 3) ^ gc) & 7) << 3) + (k & 7);
        blob[W_R + dst] = f2bf(R[idx]);
    }
    for (int idx = gid; idx < 4096; idx += stride) {
        int d = idx >> 8, gc = idx & 255;
        int dst = gc * 16 + ((((d >> 3) ^ gc) & 1) << 3) + (d & 7);
        blob[W_K + dst] = f2bf(Kw[idx]);
    }
    float* bf = (float*)(blob + W_USH);
    if (gid < 64) { bf[gid] = bh[gid]; bf[64+gid] = bc[gid]; bf[128+gid] = bgh[gid]; bf[192+gid] = bgc[gid]; }
    if (gid < 256) bf[256 + gid] = bl[gid];
}

// ---- Prologue: X_0^T (bf16, slot 0), h_lstm_0, c_lstm_0 ----
__global__ __launch_bounds__(64) void prologue_kernel(
    const float* __restrict__ xin, const float* __restrict__ h0,
    const float* __restrict__ c0,
    const float* __restrict__ Wgh, const float* __restrict__ bgh,
    const float* __restrict__ Wgc, const float* __restrict__ bgc,
    const float* __restrict__ K, const float* __restrict__ R,
    const float* __restrict__ bl,
    ushort_t* __restrict__ Xt, float* __restrict__ hl, float* __restrict__ cl)
{
    const int n = blockIdx.x;
    const int j = threadIdx.x;
    __shared__ float hs[H_], cs[H_], xs[D_];
    hs[j] = h0[n * H_ + j];
    cs[j] = c0[n * H_ + j];
    if (j < D_) xs[j] = xin[(size_t)n * T_ * D_ + j];
    __syncthreads();

    float xh = bgh[j], xc = bgc[j];
    for (int k = 0; k < H_; k++) {
        xh += hs[k] * Wgh[k * H_ + j];
        xc += cs[k] * Wgc[k * H_ + j];
    }
    Xt[(size_t)j * N_ + n]        = f2bf(xh);
    Xt[(size_t)(H_ + j) * N_ + n] = f2bf(xc);

    float zi = bl[j], zf = bl[H_ + j], zg = bl[2 * H_ + j], zo = bl[3 * H_ + j];
    for (int d = 0; d < D_; d++) {
        float xv = xs[d];
        zi += xv * K[d * 256 + j];
        zf += xv * K[d * 256 + 64 + j];
        zg += xv * K[d * 256 + 128 + j];
        zo += xv * K[d * 256 + 192 + j];
    }
    for (int k = 0; k < H_; k++) {
        float hv = hs[k];
        zi += hv * R[k * 256 + j];
        zf += hv * R[k * 256 + 64 + j];
        zg += hv * R[k * 256 + 128 + j];
        zo += hv * R[k * 256 + 192 + j];
    }
    float clv = sig_(zf) * cs[j] + sig_(zi) * tanh_(zg);
    float hlv = sig_(zo) * tanh_(clv);
    cl[n * H_ + j] = clv;
    hl[n * H_ + j] = hlv;
}

// ---- Persistent kernel ----
template<bool DEEP>
__global__ __launch_bounds__(NTHR, 4) void persistent_kernel(
    const ushort_t* __restrict__ Abf,
    ushort_t* __restrict__ Xs,
    const float* __restrict__ hl, const float* __restrict__ clm,
    const float* __restrict__ xin,
    const ushort_t* __restrict__ Wblob,
    float* __restrict__ oh, float* __restrict__ oc,
    unsigned* __restrict__ cnt)
{
    __shared__ __align__(16) ushort_t WL[WL_USH];     // 82 KB weights+biases (no W_K)
    __shared__ __align__(16) ushort_t Xw[16384];      // 32 KB: 8 waves x 4 slots x 1KB
    __shared__ __align__(16) float partB[8192];       // 32 KB partials; Gs=partB[0:1024); XBf=partB+1024
    __shared__ __align__(16) float HLs[512], CLs[512], HNs[512], CNs[512];
    __shared__ __align__(16) float XSs[128];

    const int tid  = threadIdx.x;
    const int brow = blockIdx.x * BM;
    const int wave = tid >> 6;
    const int lane = tid & 63;

    // ---- one-time staging: weights (82 x 1KB) + h/c state ----
    for (int i = wave; i < 82; i += 16) {
        int srcb = (i < 80) ? i * 1024 : (90112 + (i - 80) * 1024);
        gload16((const char*)Wblob + srcb + lane * 16, (char*)WL + i * 1024);
    }
    if (wave == 8) {
        gload16((const char*)(hl + (size_t)brow * H_) + lane * 16, (char*)HLs);
        gload16((const char*)(hl + (size_t)brow * H_) + 1024 + lane * 16, (char*)HLs + 1024);
    }
    if (wave == 9) {
        gload16((const char*)(clm + (size_t)brow * H_) + lane * 16, (char*)CLs);
        gload16((const char*)(clm + (size_t)brow * H_) + 1024 + lane * 16, (char*)CLs + 1024);
    }

    // ---- one-time: persistent A-fragments in VGPRs (waves 0-7; k-slice = wave*256) ----
    bf16x8 areg[8];
    if (wave < 8) {
        const ushort_t* ab = Abf + (size_t)(brow + (lane & 7)) * N_ + wave * 256 + (lane >> 4) * 8;
        #pragma unroll
        for (int ks = 0; ks < 8; ks++)
            areg[ks] = *(const bf16x8*)(ab + ks * 32);
    }
    __syncthreads();   // weights/state staged (vmcnt drained at barrier)

    const float* BL = (const float*)(WL + 40960);
    float* XBf = partB + 1024;

    for (int t = 0; t < T_; t++) {
        const ushort_t* Xc = Xs + (size_t)(DEEP ? t : (t & 1)) * SLOT_USH;
        ushort_t*       Xn = Xs + (size_t)(DEEP ? (t + 1) : ((t + 1) & 1)) * SLOT_USH;

        if (wave < 8) {
            // ---- GEMM: wave = k-slice owner; X via wave-local gload16 pipeline ----
            f32x4 acc[8];
            #pragma unroll
            for (int i = 0; i < 8; i++) acc[i] = (f32x4){0.f, 0.f, 0.f, 0.f};
            ushort_t* myslot = &Xw[wave * 2048];             // 4 slots x 512 ush
            const int rdoff = (lane & 15) * 32 + (lane >> 4) * 8;  // ush offset in slot

            if constexpr (DEEP) {
                const ushort_t* gbase = Xc + wave * 256 + (lane & 3) * 8;
                const int colr = lane >> 2;
                #define ISSUE(q) gload16(gbase + (size_t)(((q) & 7) * 16 + colr) * N_ + ((q) >> 3) * 32, \
                                         (char*)(myslot + ((q) & 3) * 512))
                ISSUE(0); ISSUE(1); ISSUE(2);
                #pragma unroll
                for (int ks = 0; ks < 8; ks++) {
                    #pragma unroll
                    for (int ct = 0; ct < 8; ct++) {
                        const int q = ks * 8 + ct;
                        if (q < 62)       asm volatile("s_waitcnt vmcnt(2)" ::: "memory");
                        else if (q == 62) asm volatile("s_waitcnt vmcnt(1)" ::: "memory");
                        else              asm volatile("s_waitcnt vmcnt(0)" ::: "memory");
                        __builtin_amdgcn_sched_barrier(0);
                        bf16x8 b = *(const bf16x8*)(myslot + (q & 3) * 512 + rdoff);
                        acc[ct] = __builtin_amdgcn_mfma_f32_16x16x32_bf16(areg[ks], b, acc[ct], 0, 0, 0);
                        if (q + 3 < 64) ISSUE(q + 3);
                        __builtin_amdgcn_sched_barrier(0);
                    }
                }
                #undef ISSUE
            } else {
                // fallback: uncached agent-scope loads (correct w/o fresh slots)
                #pragma unroll
                for (int ks = 0; ks < 8; ks++) {
                    #pragma unroll
                    for (int ct = 0; ct < 8; ct++) {
                        const ushort_t* p = Xc + (size_t)(ct * 16 + (lane & 15)) * N_
                                          + wave * 256 + ks * 32 + (lane >> 4) * 8;
                        union { unsigned long long q[2]; bf16x8 v; } ub;
                        ub.q[0] = __hip_atomic_load((const unsigned long long*)p,
                                                    __ATOMIC_RELAXED, __HIP_MEMORY_SCOPE_AGENT);
                        ub.q[1] = __hip_atomic_load(((const unsigned long long*)p) + 1,
                                                    __ATOMIC_RELAXED, __HIP_MEMORY_SCOPE_AGENT);
                        acc[ct] = __builtin_amdgcn_mfma_f32_16x16x32_bf16(areg[ks], ub.v, acc[ct], 0, 0, 0);
                    }
                }
            }
            // write this k-slice's partial plane (lanes 0-31 hold real rows 0-7)
            if (lane < 32) {
                float* pb = &partB[wave * 1024];
                const int mrow = (lane >> 4) * 4;
                const int cc = lane & 15;
                #pragma unroll
                for (int ct = 0; ct < 8; ct++)
                    #pragma unroll
                    for (int r = 0; r < 4; r++)
                        pb[(mrow + r) * C2_ + ct * 16 + cc] = acc[ct][r];
            }
        } else if (wave == 8) {
            if (t + 1 < T_ && lane < 32) {
                const float* g = xin + (size_t)(brow + (lane >> 2)) * (T_ * D_)
                                     + (size_t)(t + 1) * D_ + (lane & 3) * 4;
                gload16(g, (char*)XSs);
            }
        }
        __syncthreads();

        // ---- 8-way reduce + tanh -> Gs (in place over partB[0:1024)) ----
        {
            float s = partB[tid];
            #pragma unroll
            for (int p = 1; p < 8; p++) s += partB[p * 1024 + tid];
            partB[tid] = tanh_(s);
        }
        __syncthreads();

        // ---- epilogue A: h_new / c_new + output store (waves 0-7) ----
        if (tid < 512) {
            const int c = tid & 63;
            const int r = tid >> 6;
            const int swz = c & 7;
            float ah = BL[c], ac = BL[64 + c];
            #pragma unroll
            for (int kk = 0; kk < 8; kk++) {
                const int pc = ((kk ^ swz) << 3);
                uint4 w1 = *(const uint4*)&WL[W_HC + c * 64 + pc];
                uint4 w2 = *(const uint4*)&WL[W_HP + c * 64 + pc];
                uint4 w3 = *(const uint4*)&WL[W_CC + c * 64 + pc];
                uint4 w4 = *(const uint4*)&WL[W_CP + c * 64 + pc];
                const float* hb = &HLs[r * 64 + kk * 8];
                const float* gh = &partB[r * C2_ + kk * 8];
                const float* cb = &CLs[r * 64 + kk * 8];
                const float* gc = &partB[r * C2_ + 64 + kk * 8];
                const unsigned* u1 = (const unsigned*)&w1;
                const unsigned* u2 = (const unsigned*)&w2;
                const unsigned* u3 = (const unsigned*)&w3;
                const unsigned* u4 = (const unsigned*)&w4;
                #pragma unroll
                for (int q = 0; q < 4; q++) {
                    ah += blo(u1[q]) * hb[2*q] + bhi(u1[q]) * hb[2*q+1];
                    ah += blo(u2[q]) * gh[2*q] + bhi(u2[q]) * gh[2*q+1];
                    ac += blo(u3[q]) * cb[2*q] + bhi(u3[q]) * cb[2*q+1];
                    ac += blo(u4[q]) * gc[2*q] + bhi(u4[q]) * gc[2*q+1];
                }
            }
            float hnv = sig_(ah), cnv = sig_(ac);
            HNs[r * 64 + c] = hnv;
            CNs[r * 64 + c] = cnv;
            size_t o = (size_t)(brow + r) * (T_ * H_) + (size_t)t * H_ + c;
            oh[o] = hnv;
            oc[o] = cnv;
        }

        if (t + 1 == T_) break;
        __syncthreads();

        if (tid >= 512) {
            // ---- epilogue B (waves 8-15): X_{t+1} -> XBf ----
            const int tt = tid - 512;
            const int j  = tt & 127;
            const int rp = tt >> 7;   // rows rp, rp+4
            const int jj = j & 63;
            const float* S = (j < 64) ? HNs : CNs;
            float bias = (j < 64) ? BL[128 + jj] : BL[192 + jj];
            float a0 = bias, a1 = bias;
            const int swz = j & 7;
            #pragma unroll
            for (int kk = 0; kk < 8; kk++) {
                const int pc = ((kk ^ swz) << 3);
                uint4 w = *(const uint4*)&WL[W_G + j * 64 + pc];
                const unsigned* u = (const unsigned*)&w;
                const float* s0 = &S[rp * 64 + kk * 8];
                const float* s1 = &S[(rp + 4) * 64 + kk * 8];
                #pragma unroll
                for (int q = 0; q < 4; q++) {
                    a0 += blo(u[q]) * s0[2*q] + bhi(u[q]) * s0[2*q+1];
                    a1 += blo(u[q]) * s1[2*q] + bhi(u[q]) * s1[2*q+1];
                }
            }
            XBf[j * 9 + rp]     = a0;
            XBf[j * 9 + rp + 4] = a1;
        } else {
            // ---- epilogue C (waves 0-7): h_lstm/c_lstm for t+1 ----
            const int c = tid & 63;
            const int r = tid >> 6;
            float z[4];
            #pragma unroll
            for (int g = 0; g < 4; g++) z[g] = BL[256 + g * 64 + c];
            const int swz1 = c & 1, swz = c & 7;
            #pragma unroll
            for (int g = 0; g < 4; g++) {
                const ushort_t* Krow = Wblob + W_K + (g * 64 + c) * 16;  // GLOBAL (L2-hot)
                #pragma unroll
                for (int dd = 0; dd < 2; dd++) {
                    const int pc = ((dd ^ swz1) << 3);
                    uint4 w = *(const uint4*)&Krow[pc];
                    const unsigned* u = (const unsigned*)&w;
                    const float* xb = &XSs[r * 16 + dd * 8];
                    #pragma unroll
                    for (int q = 0; q < 4; q++)
                        z[g] += blo(u[q]) * xb[2*q] + bhi(u[q]) * xb[2*q+1];
                }
                const ushort_t* Rrow = &WL[W_R + (g * 64 + c) * 64];
                #pragma unroll
                for (int kk = 0; kk < 8; kk++) {
                    const int pc = ((kk ^ swz) << 3);
                    uint4 w = *(const uint4*)&Rrow[pc];
                    const unsigned* u = (const unsigned*)&w;
                    const float* hb = &HNs[r * 64 + kk * 8];
                    #pragma unroll
                    for (int q = 0; q < 4; q++)
                        z[g] += blo(u[q]) * hb[2*q] + bhi(u[q]) * hb[2*q+1];
                }
            }
            float clv = sig_(z[1]) * CNs[r * 64 + c] + sig_(z[0]) * tanh_(z[2]);
            float hlv = sig_(z[3]) * tanh_(clv);
            CLs[r * 64 + c] = clv;
            HLs[r * 64 + c] = hlv;
        }
        __syncthreads();

        // ---- store X_{t+1}^T: 8B agent-scope stores (waves 8-11) ----
        if (tid >= 512 && tid < 768) {
            const int tt   = tid - 512;
            const int j    = tt >> 1;
            const int half = tt & 1;
            const float* Xb = &XBf[j * 9 + half * 4];
            unsigned long long v =  (unsigned long long)f2bf(Xb[0])
                                 | ((unsigned long long)f2bf(Xb[1]) << 16)
                                 | ((unsigned long long)f2bf(Xb[2]) << 32)
                                 | ((unsigned long long)f2bf(Xb[3]) << 48);
            __hip_atomic_store((unsigned long long*)(Xn + (size_t)j * N_ + brow + half * 4),
                               v, __ATOMIC_RELAXED, __HIP_MEMORY_SCOPE_AGENT);
        }
        __syncthreads();   // drains X stores (vmcnt 0 before barrier)

        // ---- fence-free grid barrier ----
        if (tid == 0) {
            __hip_atomic_fetch_add(cnt, 1u, __ATOMIC_RELAXED, __HIP_MEMORY_SCOPE_AGENT);
            const unsigned target = (unsigned)NBLK * (unsigned)(t + 1);
            while (__hip_atomic_load(cnt, __ATOMIC_RELAXED, __HIP_MEMORY_SCOPE_AGENT) < target)
                __builtin_amdgcn_s_sleep(2);
        }
        __syncthreads();
        asm volatile("" ::: "memory");
    }
}

extern "C" void kernel_launch(void* const* d_in, const int* in_sizes, int n_in,
                              void* d_out, int out_size, void* d_ws, size_t ws_size,
                              hipStream_t stream) {
    const float* xin = (const float*)d_in[0];
    const float* h0  = (const float*)d_in[1];
    const float* c0  = (const float*)d_in[2];
    const float* A   = (const float*)d_in[3];
    const float* Wgh = (const float*)d_in[4];
    const float* bgh = (const float*)d_in[5];
    const float* Wgc = (const float*)d_in[6];
    const float* bgc = (const float*)d_in[7];
    const float* Whc = (const float*)d_in[8];
    const float* Whp = (const float*)d_in[9];
    const float* bh  = (const float*)d_in[10];
    const float* Wcc = (const float*)d_in[11];
    const float* Wcp = (const float*)d_in[12];
    const float* bc  = (const float*)d_in[13];
    const float* K   = (const float*)d_in[14];
    const float* R   = (const float*)d_in[15];
    const float* bl  = (const float*)d_in[16];

    const size_t fixed = (size_t)N_ * N_ * 2
                       + (size_t)N_ * H_ * 4 * 2
                       + BLOB_BYTES + 256;
    const size_t slot_bytes = SLOT_USH * 2;
    const bool deep = ws_size >= fixed + (size_t)(T_ + 1) * slot_bytes;
    const int nslots = deep ? (T_ + 1) : 2;

    char* w = (char*)d_ws;
    ushort_t* Abf  = (ushort_t*)w;  w += (size_t)N_ * N_ * 2;
    ushort_t* Xs   = (ushort_t*)w;  w += (size_t)nslots * slot_bytes;
    float* hl      = (float*)w;     w += (size_t)N_ * H_ * 4;
    float* cl      = (float*)w;     w += (size_t)N_ * H_ * 4;
    ushort_t* blob = (ushort_t*)w;  w += BLOB_BYTES;
    unsigned* cnt  = (unsigned*)w;  w += 256;

    float* oh = (float*)d_out;
    float* oc = oh + (size_t)N_ * T_ * H_;

    convert_A_kernel<<<(N_ * N_) / (256 * 4), 256, 0, stream>>>(A, Abf, cnt);
    convert_W_kernel<<<16, 256, 0, stream>>>(Whc, Whp, Wcc, Wcp, Wgh, Wgc, R, K,
                                             bh, bc, bgh, bgc, bl, blob);
    prologue_kernel<<<N_, 64, 0, stream>>>(xin, h0, c0, Wgh, bgh, Wgc, bgc,
                                           K, R, bl, Xs, hl, cl);

    void* args[] = { (void*)&Abf, (void*)&Xs, (void*)&hl, (void*)&cl,
                     (void*)&xin, (void*)&blob, (void*)&oh, (void*)&oc, (void*)&cnt };
    if (deep)
        hipLaunchCooperativeKernel((const void*)persistent_kernel<true>,
                                   dim3(NBLK), dim3(NTHR), args, 0, stream);
    else
        hipLaunchCooperativeKernel((const void*)persistent_kernel<false>,
                                   dim3(NBLK), dim3(NTHR), args, 0, stream);
}